// Round 9
// baseline (192.272 us; speedup 1.0000x reference)
//
#include <hip/hip_runtime.h>
#include <math.h>

// QuadraticAttention on MI355X — round 20: re-run of r19 (infra failure,
// no kernel signal; vmcnt ledgers re-audited clean).
// r19 changes vs r18: (1) qkvz K-loop unrolled x3 with LITERAL buffer
// indices -> ds_read becomes shared-addr + imm offset, kills cbuf/sbuf
// VALU bookkeeping (r18: VALUBusy 35% vs MFMA 20%). (2) gemm_out was the
// last 1-block/CU kernel (grid 256): tile 128x128 -> 64x128, grid (8,64)
// =512 = 2 blk/CU, 36KB LDS, wave 32x64, static 3-buf vmcnt(3) pipeline.
// attn (r18 QBLK=64 + setprio + balanced remap), cvt unchanged.

typedef float  f32x4  __attribute__((ext_vector_type(4)));
typedef short  bf16x8 __attribute__((ext_vector_type(8)));
typedef float  vf4    __attribute__((ext_vector_type(4)));
typedef unsigned short u16x4 __attribute__((ext_vector_type(4)));

static __device__ __forceinline__ unsigned short f2bf(float f) {
    union { float f; unsigned int i; } c; c.f = f;
    unsigned int x = c.i;
    return (unsigned short)((x + 0x7fffu + ((x >> 16) & 1u)) >> 16);
}
static __device__ __forceinline__ f32x4 shfl_xor4(f32x4 v, int m) {
    f32x4 r;
    r[0] = __shfl_xor(v[0], m); r[1] = __shfl_xor(v[1], m);
    r[2] = __shfl_xor(v[2], m); r[3] = __shfl_xor(v[3], m);
    return r;
}
static __device__ __forceinline__ f32x4 rsq4(f32x4 v) {
    f32x4 r;
#pragma unroll
    for (int i = 0; i < 4; i++) r[i] = rsqrtf(v[i] * (1.0f / 64.0f) + 1.1920929e-07f);
    return r;
}
// async 16B/lane global -> LDS
static __device__ __forceinline__ void cp16(const unsigned short* g, unsigned short* l) {
    __builtin_amdgcn_global_load_lds(
        (const __attribute__((address_space(1))) unsigned int*)g,
        (__attribute__((address_space(3))) unsigned int*)l, 16, 0, 0);
}

#define FOR_M(X)  X(0) X(1) X(2) X(3)
#define FOR_MN(X) X(0,0) X(0,1) X(0,2) X(0,3) X(1,0) X(1,1) X(1,2) X(1,3) \
                  X(2,0) X(2,1) X(2,2) X(2,3) X(3,0) X(3,1) X(3,2) X(3,3)
#define FOR_MN2(X) X(0,0) X(0,1) X(0,2) X(0,3) X(1,0) X(1,1) X(1,2) X(1,3)

#define MF(c,a,b) c = __builtin_amdgcn_mfma_f32_16x16x32_bf16(a, b, c, 0, 0, 0);

#define VMC4 asm volatile("s_waitcnt vmcnt(4)" ::: "memory");
#define VMC3 asm volatile("s_waitcnt vmcnt(3)" ::: "memory");
#define VMC0 asm volatile("s_waitcnt vmcnt(0)" ::: "memory");
#define LGC0 asm volatile("s_waitcnt lgkmcnt(0)" ::: "memory");
#define BARR __builtin_amdgcn_s_barrier();

// ---------------------------------------------------------------------------
__global__ __launch_bounds__(256) void cvt_all(
    const float* __restrict__ x,  const float* __restrict__ Wq,
    const float* __restrict__ Wk, const float* __restrict__ Wv,
    const float* __restrict__ Wo,
    unsigned short* __restrict__ xb,  unsigned short* __restrict__ Wqb,
    unsigned short* __restrict__ Wkb, unsigned short* __restrict__ Wvb,
    unsigned short* __restrict__ Wob, int nx4, int nw4)
{
    int i = blockIdx.x * 256 + threadIdx.x;
    const float* s; unsigned short* d; int li;
    if (i < nx4) { s = x; d = xb; li = i; }
    else {
        int idx = i - nx4;
        int r = idx / nw4; li = idx - r * nw4;
        if (r >= 4) return;
        s = (r == 0) ? Wq : (r == 1) ? Wk : (r == 2) ? Wv : Wo;
        d = (r == 0) ? Wqb : (r == 1) ? Wkb : (r == 2) ? Wvb : Wob;
    }
    vf4 v = *(const vf4*)(s + (size_t)li * 4);
    u16x4 o;
#pragma unroll
    for (int j = 0; j < 4; j++) o[j] = f2bf(v[j]);
    *(u16x4*)(d + (size_t)li * 4) = o;
}

// ---------------------------------------------------------------------------
#define SS 136   // epilogue stage row stride (elems)

// ---------------------------------------------------------------------------
// Per-matrix GEMM (z = 0:q 1:k 2:v). 256 threads / 4 waves, 128x128 tile,
// wave (wy,wx) owns 64m x 64n. BK=32, 3-buffer depth-2 counted-vmcnt
// pipeline with STATIC buffer indices (K-loop unrolled x3). 768 blocks =
// 3 blocks/CU (48KB LDS each).
// ---------------------------------------------------------------------------
__global__ __launch_bounds__(256, 3) void gemm_qkvz(
    const unsigned short* __restrict__ xb,
    const unsigned short* __restrict__ Wqb,
    const unsigned short* __restrict__ Wkb,
    const unsigned short* __restrict__ Wvb,
    const float* __restrict__ bqf, const float* __restrict__ bkf, const float* __restrict__ bvf,
    const float* __restrict__ nwp,
    unsigned short* __restrict__ qb, unsigned short* __restrict__ kb,
    unsigned short* __restrict__ vT)
{
    const int K = 1024;
    __shared__ unsigned short smem[24576];   // 48KB: 3 staging bufs (16KB); epi stage aliases
    const int z = blockIdx.z;
    const unsigned short* Wb = (z == 0) ? Wqb : (z == 1) ? Wkb : Wvb;
    const float* bias = (z == 0) ? bqf : (z == 1) ? bkf : bvf;
    const int tid = threadIdx.x;
    const int n0 = blockIdx.x * 128;
    const int m0 = blockIdx.y * 128;
    const int lane = tid & 63, wid = tid >> 6;   // 4 waves
    const int wy = wid >> 1, wx = wid & 1;       // wave = 64m x 64n
    const int l15 = lane & 15, quad = lane >> 4;
    const int r16 = lane >> 2;
    const int c8  = (lane & 3) * 8;

#define Z_DECL_ACC(mi,ni) f32x4 c##mi##ni = {0.f, 0.f, 0.f, 0.f};
    FOR_MN(Z_DECL_ACC)

#define Z_STAGE(BUF, KT) { \
        unsigned short* dstb = smem + (BUF) * 8192; \
        _Pragma("unroll") \
        for (int j = 0; j < 4; j++) { \
            const int ch = wid * 4 + j;          /* 0..15, 16 rows each */ \
            const int mat = ch >> 3;             /* 0:A(x) 1:W */ \
            const int row = (ch & 7) * 16 + r16; \
            const unsigned short* g = mat \
                ? Wb + (size_t)(n0 + row) * K + (KT) + c8 \
                : xb + (size_t)(m0 + row) * K + (KT) + c8; \
            cp16(g, &dstb[ch * 512]); \
        } }

#define Z_COMPUTE(BUF) { \
        const unsigned short* As_ = smem + (BUF) * 8192; \
        const unsigned short* Bs_ = As_ + 4096; \
        const bf16x8 a0 = *(const bf16x8*)&As_[(wy * 64 +  0 + l15) * 32 + quad * 8]; \
        const bf16x8 a1 = *(const bf16x8*)&As_[(wy * 64 + 16 + l15) * 32 + quad * 8]; \
        const bf16x8 a2 = *(const bf16x8*)&As_[(wy * 64 + 32 + l15) * 32 + quad * 8]; \
        const bf16x8 a3 = *(const bf16x8*)&As_[(wy * 64 + 48 + l15) * 32 + quad * 8]; \
        const bf16x8 b0 = *(const bf16x8*)&Bs_[(wx * 64 +  0 + l15) * 32 + quad * 8]; \
        const bf16x8 b1 = *(const bf16x8*)&Bs_[(wx * 64 + 16 + l15) * 32 + quad * 8]; \
        const bf16x8 b2 = *(const bf16x8*)&Bs_[(wx * 64 + 32 + l15) * 32 + quad * 8]; \
        const bf16x8 b3 = *(const bf16x8*)&Bs_[(wx * 64 + 48 + l15) * 32 + quad * 8]; \
        MF(c00,a0,b0) MF(c01,a0,b1) MF(c02,a0,b2) MF(c03,a0,b3) \
        MF(c10,a1,b0) MF(c11,a1,b1) MF(c12,a1,b2) MF(c13,a1,b3) \
        MF(c20,a2,b0) MF(c21,a2,b1) MF(c22,a2,b2) MF(c23,a2,b3) \
        MF(c30,a3,b0) MF(c31,a3,b1) MF(c32,a3,b2) MF(c33,a3,b3) }

    // ---- pipelined K-loop: 32 tiles, depth-2 prefetch, static 3-buf ----
    // tile t lives in buf t%3; schedule per tile: vmcnt(4); barrier;
    // stage(t+2); compute(t); lgkmcnt(0).
    Z_STAGE(0, 0)
    Z_STAGE(1, 32)
    for (int p = 0; p < 10; ++p) {
        const int t = p * 3;
        VMC4 BARR Z_STAGE(2, (t + 2) * 32) Z_COMPUTE(0) LGC0
        VMC4 BARR Z_STAGE(0, (t + 3) * 32) Z_COMPUTE(1) LGC0
        VMC4 BARR Z_STAGE(1, (t + 4) * 32) Z_COMPUTE(2) LGC0
    }
    VMC4 BARR Z_COMPUTE(0) LGC0          // tile 30
    VMC0 BARR Z_COMPUTE(1)               // tile 31
    __syncthreads();   // full drain once; smem reused as epilogue stage

    // bias (all paths)
    const float bs0 = bias[n0 + wx * 64 + l15];
    const float bs1 = bias[n0 + wx * 64 + 16 + l15];
    const float bs2 = bias[n0 + wx * 64 + 32 + l15];
    const float bs3 = bias[n0 + wx * 64 + 48 + l15];
#define Z_BIAS(mi) c##mi##0 += bs0; c##mi##1 += bs1; c##mi##2 += bs2; c##mi##3 += bs3;
    FOR_M(Z_BIAS)

    if (z < 2) {
        // ---- q/k: rmsnorm (per 64-dim head row) + rope + store ----
        const float nww0 = nwp[l15],      nww1 = nwp[16 + l15];
        const float nww2 = nwp[32 + l15], nww3 = nwp[48 + l15];
        const float lf0 = expf(-(float)l15 * 0.28782313662425572f);      // ln(1e4)/32
        const float lf1 = expf(-(float)(l15 + 16) * 0.28782313662425572f);

#define Z_S2(mi) f32x4 s2_##mi = c##mi##0*c##mi##0 + c##mi##1*c##mi##1 + \
                                 c##mi##2*c##mi##2 + c##mi##3*c##mi##3; \
        s2_##mi = s2_##mi + shfl_xor4(s2_##mi, 1); \
        s2_##mi = s2_##mi + shfl_xor4(s2_##mi, 2); \
        s2_##mi = s2_##mi + shfl_xor4(s2_##mi, 4); \
        s2_##mi = s2_##mi + shfl_xor4(s2_##mi, 8); \
        s2_##mi = rsq4(s2_##mi);
        FOR_M(Z_S2)

#define Z_ROPE_ONE(mi,ni,NW,CS,SN) { \
            float vn = c##mi##ni[r] * s2v[r] * NW; \
            float pt = __shfl_xor(vn, 1); \
            float rot = (lane & 1) ? pt : -pt; \
            smem[mrow * SS + wx * 64 + (ni) * 16 + l15] = f2bf((vn * (CS) + rot * (SN)) * 0.125f); }
#define Z_ROPE_MI(mi) { f32x4 s2v = s2_##mi; \
            _Pragma("unroll") \
            for (int r = 0; r < 4; r++) { \
                const int mrow = wy * 64 + (mi) * 16 + quad * 4 + r; \
                const float t = (float)((m0 + mrow) & 2047); \
                const float a0 = t * lf0, a1 = t * lf1; \
                const float cs0 = cosf(a0), sn0 = sinf(a0); \
                const float cs1 = cosf(a1), sn1 = sinf(a1); \
                Z_ROPE_ONE(mi,0,nww0,cs0,sn0) Z_ROPE_ONE(mi,1,nww1,cs1,sn1) \
                Z_ROPE_ONE(mi,2,nww2,cs0,sn0) Z_ROPE_ONE(mi,3,nww3,cs1,sn1) } }
        FOR_M(Z_ROPE_MI)

        __syncthreads();
        unsigned short* dst = z ? kb : qb;
#pragma unroll
        for (int it = 0; it < 8; it++) {
            const int linear = tid + it * 256;
            const int row = linear >> 4, cb = linear & 15;
            *(bf16x8*)(dst + (size_t)(m0 + row) * 1024 + n0 + cb * 8) =
                *(const bf16x8*)&smem[row * SS + cb * 8];
        }
    } else {
        // ---- v: transposed per-head store ----
#define Z_VST(mi,ni) { _Pragma("unroll") \
            for (int r = 0; r < 4; r++) { \
                const int mrow = wy * 64 + (mi) * 16 + quad * 4 + r; \
                smem[(wx * 64 + (ni) * 16 + l15) * SS + mrow] = f2bf(c##mi##ni[r]); } }
        FOR_MN(Z_VST)
        __syncthreads();
        const int b = m0 >> 11, tok0 = m0 & 2047;
#pragma unroll
        for (int it = 0; it < 8; it++) {
            const int linear = tid + it * 256;
            const int rowd = linear >> 4, cb = linear & 15;
            const int head_g = (n0 >> 6) + (rowd >> 6);
            const int d = rowd & 63;
            *(bf16x8*)(vT + (((size_t)b * 16 + head_g) * 64 + d) * 2048 + tok0 + cb * 8) =
                *(const bf16x8*)&smem[rowd * SS + cb * 8];
        }
    }
}

// ---------------------------------------------------------------------------
// Output GEMM + residual. r19: 64x128 tile, grid (8,64)=512 = 2 blocks/CU,
// 256 threads / 4 waves, wave 32m x 64n (8 accs). 3-buf (36KB) static
// counted-vmcnt(3) pipeline. Epilogue: f32 residual add.
// ---------------------------------------------------------------------------
__global__ __launch_bounds__(256, 4) void gemm_out(
    const unsigned short* __restrict__ zb,
    const unsigned short* __restrict__ Wob,
    const float* __restrict__ x, float* __restrict__ out, int M)
{
    const int K = 1024;
    __shared__ unsigned short smem[18432];   // 3 bufs x (A[64][32] + W[128][32]) = 36KB
    const int tid = threadIdx.x;
    const int n0 = blockIdx.x * 128;
    const int m0 = blockIdx.y * 64;
    const int lane = tid & 63, wid = tid >> 6;
    const int wy = wid >> 1, wx = wid & 1;       // wave = 32m x 64n
    const int l15 = lane & 15, quad = lane >> 4;

#define G_DECL_ACC(mi,ni) f32x4 c##mi##ni = {0.f, 0.f, 0.f, 0.f};
    FOR_MN2(G_DECL_ACC)

// 3 cp16/thread: 1 A chunk (64 rows x 4), 2 W chunks (128 rows x 4)
#define O_STAGE(BUF, KT) { \
        unsigned short* dstb = smem + (BUF) * 6144; \
        { const int row = tid >> 2, ch = tid & 3; \
          cp16(zb + (size_t)(m0 + row) * K + (KT) + ch * 8, &dstb[row * 32 + ch * 8]); } \
        _Pragma("unroll") \
        for (int jb = 0; jb < 2; jb++) { \
            const int u = tid + jb * 256; \
            const int row = u >> 2, ch = u & 3; \
            cp16(Wob + (size_t)(n0 + row) * K + (KT) + ch * 8, \
                 &dstb[2048 + row * 32 + ch * 8]); \
        } }

#define O_COMPUTE(BUF) { \
        const unsigned short* As_ = smem + (BUF) * 6144; \
        const unsigned short* Bs_ = As_ + 2048; \
        const bf16x8 a0 = *(const bf16x8*)&As_[(wy * 32 +  0 + l15) * 32 + quad * 8]; \
        const bf16x8 a1 = *(const bf16x8*)&As_[(wy * 32 + 16 + l15) * 32 + quad * 8]; \
        const bf16x8 b0 = *(const bf16x8*)&Bs_[(wx * 64 +  0 + l15) * 32 + quad * 8]; \
        const bf16x8 b1 = *(const bf16x8*)&Bs_[(wx * 64 + 16 + l15) * 32 + quad * 8]; \
        const bf16x8 b2 = *(const bf16x8*)&Bs_[(wx * 64 + 32 + l15) * 32 + quad * 8]; \
        const bf16x8 b3 = *(const bf16x8*)&Bs_[(wx * 64 + 48 + l15) * 32 + quad * 8]; \
        MF(c00,a0,b0) MF(c01,a0,b1) MF(c02,a0,b2) MF(c03,a0,b3) \
        MF(c10,a1,b0) MF(c11,a1,b1) MF(c12,a1,b2) MF(c13,a1,b3) }

    O_STAGE(0, 0)
    O_STAGE(1, 32)
    for (int p = 0; p < 10; ++p) {
        const int t = p * 3;
        VMC3 BARR O_STAGE(2, (t + 2) * 32) O_COMPUTE(0) LGC0
        VMC3 BARR O_STAGE(0, (t + 3) * 32) O_COMPUTE(1) LGC0
        VMC3 BARR O_STAGE(1, (t + 4) * 32) O_COMPUTE(2) LGC0
    }
    VMC3 BARR O_COMPUTE(0) LGC0          // tile 30
    VMC0 BARR O_COMPUTE(1)               // tile 31

#define G_OUTST(mi,ni) { _Pragma("unroll") \
        for (int r = 0; r < 4; r++) { \
            const int m = m0 + wy * 32 + (mi) * 16 + quad * 4 + r; \
            const int n = n0 + wx * 64 + (ni) * 16 + l15; \
            out[(size_t)m * 1024 + n] = c##mi##ni[r] + x[(size_t)m * 1024 + n]; } }
    FOR_MN2(G_OUTST)
}

// ---------------------------------------------------------------------------
// Causal quadratic attention. r18: QBLK=64 (4 waves x 16 q-rows), grid
// 1024 = 32 qt x 32 bh, 4 blocks/CU, balanced half-remap (31-x, x).
// setprio around MFMA clusters. Mask only at kt==qt. (unchanged)
// ---------------------------------------------------------------------------
__global__ __launch_bounds__(256, 4) void attn_mfma(
    const unsigned short* __restrict__ qb, const unsigned short* __restrict__ kb,
    const unsigned short* __restrict__ vT, unsigned short* __restrict__ zb)
{
    __shared__ unsigned short Qs[64 * 72];
    __shared__ unsigned short Ks[64 * 72];
    __shared__ unsigned short Vs[64 * 72];   // rows = d, cols = k-token
    __shared__ unsigned short Pm[64 * 72];
    const int tid = threadIdx.x;

    // ---- balance remap: qt in 0..31 (64-row tiles); pair (31-x, x) ----
    const int bid = blockIdx.x;
    const int halfsz = gridDim.x >> 1;              // 512
    const int half = (bid >= halfsz) ? 1 : 0;
    const int r = bid - half * halfsz;              // 0..511
    const int qt = half ? (r & 15) : 31 - (r & 15);
    const int bh = r >> 4;                          // 0..31

    const int b = bh >> 4, h = bh & 15;
    const int lane = tid & 63, wq = tid >> 6;       // wq 0..3: 16 q-rows each
    const int l15 = lane & 15, quad = lane >> 4;
    const size_t tokbase = (size_t)b * 2048;
    const int q0 = qt * 64;

#pragma unroll
    for (int j = 0; j < 2; j++) {
        const int u = tid + j * 256;
        const int row = u >> 3, seg = (u & 7) * 8;
        bf16x8 v = *(const bf16x8*)(qb + (tokbase + q0 + row) * 1024 + h * 64 + seg);
        *(bf16x8*)&Qs[row * 72 + seg] = v;
    }
    __syncthreads();
    const bf16x8 aq0 = *(const bf16x8*)&Qs[(wq * 16 + l15) * 72 + quad * 8];
    const bf16x8 aq1 = *(const bf16x8*)&Qs[(wq * 16 + l15) * 72 + 32 + quad * 8];

    const int kr = tid >> 3;                        // 0..31
    const int sg = (tid & 7) * 8;

    bf16x8 pk0, pk1, pv0, pv1;
#define A_GLB(KT) { \
        pk0 = *(const bf16x8*)(kb + (tokbase + (KT) * 64 + kr) * 1024 + h * 64 + sg); \
        pk1 = *(const bf16x8*)(kb + (tokbase + (KT) * 64 + kr + 32) * 1024 + h * 64 + sg); \
        pv0 = *(const bf16x8*)(vT + ((size_t)bh * 64 + kr) * 2048 + (KT) * 64 + sg); \
        pv1 = *(const bf16x8*)(vT + ((size_t)bh * 64 + kr + 32) * 2048 + (KT) * 64 + sg); }

    f32x4 z_0 = {0.f,0.f,0.f,0.f}, z_1 = {0.f,0.f,0.f,0.f};
    f32x4 z_2 = {0.f,0.f,0.f,0.f}, z_3 = {0.f,0.f,0.f,0.f};

    const int nkt = qt + 1;
    A_GLB(0)
    for (int kt = 0; kt < nkt; kt++) {
        __syncthreads();
        *(bf16x8*)&Ks[kr * 72 + sg] = pk0;
        *(bf16x8*)&Ks[(kr + 32) * 72 + sg] = pk1;
        *(bf16x8*)&Vs[kr * 72 + sg] = pv0;
        *(bf16x8*)&Vs[(kr + 32) * 72 + sg] = pv1;
        __syncthreads();
        if (kt + 1 < nkt) A_GLB(kt + 1)

        f32x4 s_0 = {0.f,0.f,0.f,0.f}, s_1 = {0.f,0.f,0.f,0.f};
        f32x4 s_2 = {0.f,0.f,0.f,0.f}, s_3 = {0.f,0.f,0.f,0.f};
#define A_QKH(KS, AQ) { \
        bf16x8 b0 = *(const bf16x8*)&Ks[(l15) * 72 + (KS) * 32 + quad * 8]; \
        bf16x8 b1 = *(const bf16x8*)&Ks[(16 + l15) * 72 + (KS) * 32 + quad * 8]; \
        bf16x8 b2 = *(const bf16x8*)&Ks[(32 + l15) * 72 + (KS) * 32 + quad * 8]; \
        bf16x8 b3 = *(const bf16x8*)&Ks[(48 + l15) * 72 + (KS) * 32 + quad * 8]; \
        MF(s_0, AQ, b0) MF(s_1, AQ, b1) MF(s_2, AQ, b2) MF(s_3, AQ, b3) }
        __builtin_amdgcn_s_setprio(1);
        A_QKH(0, aq0)
        A_QKH(1, aq1)
        __builtin_amdgcn_s_setprio(0);

        const bool needmask = (kt == qt);
#define A_PSTORE(n) { \
        f32x4 p4 = s_##n * s_##n; \
        if (needmask) { _Pragma("unroll") \
            for (int r2 = 0; r2 < 4; r2++) \
                if (kt * 64 + (n) * 16 + l15 > q0 + wq * 16 + quad * 4 + r2) p4[r2] = 0.f; } \
        _Pragma("unroll") \
        for (int r2 = 0; r2 < 4; r2++) \
            Pm[(wq * 16 + quad * 4 + r2) * 72 + (n) * 16 + l15] = f2bf(p4[r2]); }
        A_PSTORE(0) A_PSTORE(1) A_PSTORE(2) A_PSTORE(3)

#define A_PVH(KS) { \
        bf16x8 ap = *(const bf16x8*)&Pm[(wq * 16 + l15) * 72 + (KS) * 32 + quad * 8]; \
        bf16x8 u0 = *(const bf16x8*)&Vs[(l15) * 72 + (KS) * 32 + quad * 8]; \
        bf16x8 u1 = *(const bf16x8*)&Vs[(16 + l15) * 72 + (KS) * 32 + quad * 8]; \
        bf16x8 u2 = *(const bf16x8*)&Vs[(32 + l15) * 72 + (KS) * 32 + quad * 8]; \
        bf16x8 u3 = *(const bf16x8*)&Vs[(48 + l15) * 72 + (KS) * 32 + quad * 8]; \
        MF(z_0, ap, u0) MF(z_1, ap, u1) MF(z_2, ap, u2) MF(z_3, ap, u3) }
        __builtin_amdgcn_s_setprio(1);
        A_PVH(0)
        A_PVH(1)
        __builtin_amdgcn_s_setprio(0);
    }

#define A_ZST(n) { _Pragma("unroll") \
        for (int r2 = 0; r2 < 4; r2++) \
            Pm[(wq * 16 + quad * 4 + r2) * 72 + (n) * 16 + l15] = f2bf(z_##n[r2]); }
    A_ZST(0) A_ZST(1) A_ZST(2) A_ZST(3)
#pragma unroll
    for (int it = 0; it < 2; it++) {
        const int linear = it * 64 + lane;
        const int row = linear >> 3, cb = linear & 7;
        *(bf16x8*)(zb + (tokbase + q0 + wq * 16 + row) * 1024 + h * 64 + cb * 8) =
            *(const bf16x8*)&Pm[(wq * 16 + row) * 72 + cb * 8];
    }
}

// ---------------------------------------------------------------------------
extern "C" void kernel_launch(void* const* d_in, const int* in_sizes, int n_in,
                              void* d_out, int out_size, void* d_ws, size_t ws_size,
                              hipStream_t stream)
{
    const float* x  = (const float*)d_in[0];
    const float* Wq = (const float*)d_in[1];
    const float* bq = (const float*)d_in[2];
    const float* Wk = (const float*)d_in[3];
    const float* bk = (const float*)d_in[4];
    const float* Wv = (const float*)d_in[5];
    const float* bv = (const float*)d_in[6];
    const float* Wo = (const float*)d_in[7];
    const float* nw = (const float*)d_in[8];
    float* out = (float*)d_out;

    const int D = 1024;
    const int M = in_sizes[0] / D;   // B*S = 4096

    unsigned short* xbb = (unsigned short*)d_ws;         // M*D
    unsigned short* Wqb = xbb + (size_t)M * D;           // D*D
    unsigned short* Wkb = Wqb + (size_t)D * D;
    unsigned short* Wvb = Wkb + (size_t)D * D;
    unsigned short* Wob = Wvb + (size_t)D * D;
    unsigned short* qbw = Wob + (size_t)D * D;           // M*D
    unsigned short* kbw = qbw + (size_t)M * D;
    unsigned short* vTw = kbw + (size_t)M * D;
    unsigned short* zbw = vTw + (size_t)M * D;

    const int nx4 = M * D / 4, nw4 = D * D / 4;
    const int ncvt = nx4 + 4 * nw4;
    cvt_all<<<(ncvt + 255) / 256, 256, 0, stream>>>(
        x, Wq, Wk, Wv, Wo, xbb, Wqb, Wkb, Wvb, Wob, nx4, nw4);

    gemm_qkvz<<<dim3(D / 128, M / 128, 3), 256, 0, stream>>>(
        xbb, Wqb, Wkb, Wvb, bq, bk, bv, nw, qbw, kbw, vTw);

    attn_mfma<<<dim3((M / 2048) * 16 * 32), 256, 0, stream>>>(qbw, kbw, vTw, zbw);

    gemm_out<<<dim3(D / 128, M / 64), 256, 0, stream>>>(zbw, Wob, x, out, M);
}

// Round 10
// 185.459 us; speedup vs baseline: 1.0367x; 1.0367x over previous
//
#include <hip/hip_runtime.h>
#include <math.h>

// QuadraticAttention on MI355X — round 21.
// r20 post-mortem: static unroll on qkvz worked (51.7->49.0, VALU 35->28)
// but gemm_out 64x128 regressed total 185.9->192.3 (+9us: W-panel re-reads
// doubled, MFMA:read ratio halved). r21: (1) gemm_out back to r17 geometry
// (128x128, wave 64x64, 3 blk/CU) + static 3-buf unroll; (2) qkvz + T1 XCD
// swizzle: 1D grid 768, wid=(bid%8)*96+bid/8 -> each XCD's 96 blocks = 12
// m-rows x 8 n x 1 z, working set ~5MB ~ L2 (qkvz FETCH 78MB vs ~30 ideal);
// (3) attn (r18 QBLK=64 + setprio + balanced remap), cvt unchanged.

typedef float  f32x4  __attribute__((ext_vector_type(4)));
typedef short  bf16x8 __attribute__((ext_vector_type(8)));
typedef float  vf4    __attribute__((ext_vector_type(4)));
typedef unsigned short u16x4 __attribute__((ext_vector_type(4)));

static __device__ __forceinline__ unsigned short f2bf(float f) {
    union { float f; unsigned int i; } c; c.f = f;
    unsigned int x = c.i;
    return (unsigned short)((x + 0x7fffu + ((x >> 16) & 1u)) >> 16);
}
static __device__ __forceinline__ f32x4 shfl_xor4(f32x4 v, int m) {
    f32x4 r;
    r[0] = __shfl_xor(v[0], m); r[1] = __shfl_xor(v[1], m);
    r[2] = __shfl_xor(v[2], m); r[3] = __shfl_xor(v[3], m);
    return r;
}
static __device__ __forceinline__ f32x4 rsq4(f32x4 v) {
    f32x4 r;
#pragma unroll
    for (int i = 0; i < 4; i++) r[i] = rsqrtf(v[i] * (1.0f / 64.0f) + 1.1920929e-07f);
    return r;
}
// async 16B/lane global -> LDS
static __device__ __forceinline__ void cp16(const unsigned short* g, unsigned short* l) {
    __builtin_amdgcn_global_load_lds(
        (const __attribute__((address_space(1))) unsigned int*)g,
        (__attribute__((address_space(3))) unsigned int*)l, 16, 0, 0);
}

#define FOR_M(X)  X(0) X(1) X(2) X(3)
#define FOR_MN(X) X(0,0) X(0,1) X(0,2) X(0,3) X(1,0) X(1,1) X(1,2) X(1,3) \
                  X(2,0) X(2,1) X(2,2) X(2,3) X(3,0) X(3,1) X(3,2) X(3,3)

#define MF(c,a,b) c = __builtin_amdgcn_mfma_f32_16x16x32_bf16(a, b, c, 0, 0, 0);

#define VMC4 asm volatile("s_waitcnt vmcnt(4)" ::: "memory");
#define VMC0 asm volatile("s_waitcnt vmcnt(0)" ::: "memory");
#define LGC0 asm volatile("s_waitcnt lgkmcnt(0)" ::: "memory");
#define BARR __builtin_amdgcn_s_barrier();

// ---------------------------------------------------------------------------
__global__ __launch_bounds__(256) void cvt_all(
    const float* __restrict__ x,  const float* __restrict__ Wq,
    const float* __restrict__ Wk, const float* __restrict__ Wv,
    const float* __restrict__ Wo,
    unsigned short* __restrict__ xb,  unsigned short* __restrict__ Wqb,
    unsigned short* __restrict__ Wkb, unsigned short* __restrict__ Wvb,
    unsigned short* __restrict__ Wob, int nx4, int nw4)
{
    int i = blockIdx.x * 256 + threadIdx.x;
    const float* s; unsigned short* d; int li;
    if (i < nx4) { s = x; d = xb; li = i; }
    else {
        int idx = i - nx4;
        int r = idx / nw4; li = idx - r * nw4;
        if (r >= 4) return;
        s = (r == 0) ? Wq : (r == 1) ? Wk : (r == 2) ? Wv : Wo;
        d = (r == 0) ? Wqb : (r == 1) ? Wkb : (r == 2) ? Wvb : Wob;
    }
    vf4 v = *(const vf4*)(s + (size_t)li * 4);
    u16x4 o;
#pragma unroll
    for (int j = 0; j < 4; j++) o[j] = f2bf(v[j]);
    *(u16x4*)(d + (size_t)li * 4) = o;
}

// ---------------------------------------------------------------------------
#define SS 136   // epilogue stage row stride (elems)

// ---------------------------------------------------------------------------
// Per-matrix GEMM (z = 0:q 1:k 2:v). 256 threads / 4 waves, 128x128 tile,
// wave 64x64. BK=32, static 3-buffer depth-2 counted-vmcnt pipeline.
// 1D grid 768 + XCD swizzle: wid=(bid%8)*96+bid/8; decode z=wid>>8,
// m=(wid&255)>>3, n=wid&7 -> each XCD works one z, 12 m-rows, all 8 n.
// ---------------------------------------------------------------------------
__global__ __launch_bounds__(256, 3) void gemm_qkvz(
    const unsigned short* __restrict__ xb,
    const unsigned short* __restrict__ Wqb,
    const unsigned short* __restrict__ Wkb,
    const unsigned short* __restrict__ Wvb,
    const float* __restrict__ bqf, const float* __restrict__ bkf, const float* __restrict__ bvf,
    const float* __restrict__ nwp,
    unsigned short* __restrict__ qb, unsigned short* __restrict__ kb,
    unsigned short* __restrict__ vT)
{
    const int K = 1024;
    __shared__ unsigned short smem[24576];   // 48KB: 3 staging bufs (16KB); epi stage aliases
    // ---- XCD-aware remap (bijective: 768 = 8 x 96) ----
    const int lbid = blockIdx.x;
    const int wid_ = (lbid & 7) * 96 + (lbid >> 3);
    const int z = wid_ >> 8;                  // 0..2
    const int rem = wid_ & 255;
    const int m0 = (rem >> 3) * 128;
    const int n0 = (rem & 7) * 128;
    const unsigned short* Wb = (z == 0) ? Wqb : (z == 1) ? Wkb : Wvb;
    const float* bias = (z == 0) ? bqf : (z == 1) ? bkf : bvf;
    const int tid = threadIdx.x;
    const int lane = tid & 63, wid = tid >> 6;   // 4 waves
    const int wy = wid >> 1, wx = wid & 1;       // wave = 64m x 64n
    const int l15 = lane & 15, quad = lane >> 4;
    const int r16 = lane >> 2;
    const int c8  = (lane & 3) * 8;

#define Z_DECL_ACC(mi,ni) f32x4 c##mi##ni = {0.f, 0.f, 0.f, 0.f};
    FOR_MN(Z_DECL_ACC)

#define Z_STAGE(BUF, KT) { \
        unsigned short* dstb = smem + (BUF) * 8192; \
        _Pragma("unroll") \
        for (int j = 0; j < 4; j++) { \
            const int ch = wid * 4 + j;          /* 0..15, 16 rows each */ \
            const int mat = ch >> 3;             /* 0:A(x) 1:W */ \
            const int row = (ch & 7) * 16 + r16; \
            const unsigned short* g = mat \
                ? Wb + (size_t)(n0 + row) * K + (KT) + c8 \
                : xb + (size_t)(m0 + row) * K + (KT) + c8; \
            cp16(g, &dstb[ch * 512]); \
        } }

#define Z_COMPUTE(BUF) { \
        const unsigned short* As_ = smem + (BUF) * 8192; \
        const unsigned short* Bs_ = As_ + 4096; \
        const bf16x8 a0 = *(const bf16x8*)&As_[(wy * 64 +  0 + l15) * 32 + quad * 8]; \
        const bf16x8 a1 = *(const bf16x8*)&As_[(wy * 64 + 16 + l15) * 32 + quad * 8]; \
        const bf16x8 a2 = *(const bf16x8*)&As_[(wy * 64 + 32 + l15) * 32 + quad * 8]; \
        const bf16x8 a3 = *(const bf16x8*)&As_[(wy * 64 + 48 + l15) * 32 + quad * 8]; \
        const bf16x8 b0 = *(const bf16x8*)&Bs_[(wx * 64 +  0 + l15) * 32 + quad * 8]; \
        const bf16x8 b1 = *(const bf16x8*)&Bs_[(wx * 64 + 16 + l15) * 32 + quad * 8]; \
        const bf16x8 b2 = *(const bf16x8*)&Bs_[(wx * 64 + 32 + l15) * 32 + quad * 8]; \
        const bf16x8 b3 = *(const bf16x8*)&Bs_[(wx * 64 + 48 + l15) * 32 + quad * 8]; \
        MF(c00,a0,b0) MF(c01,a0,b1) MF(c02,a0,b2) MF(c03,a0,b3) \
        MF(c10,a1,b0) MF(c11,a1,b1) MF(c12,a1,b2) MF(c13,a1,b3) \
        MF(c20,a2,b0) MF(c21,a2,b1) MF(c22,a2,b2) MF(c23,a2,b3) \
        MF(c30,a3,b0) MF(c31,a3,b1) MF(c32,a3,b2) MF(c33,a3,b3) }

    // ---- pipelined K-loop: 32 tiles, depth-2 prefetch, static 3-buf ----
    Z_STAGE(0, 0)
    Z_STAGE(1, 32)
    for (int p = 0; p < 10; ++p) {
        const int t = p * 3;
        VMC4 BARR Z_STAGE(2, (t + 2) * 32) Z_COMPUTE(0) LGC0
        VMC4 BARR Z_STAGE(0, (t + 3) * 32) Z_COMPUTE(1) LGC0
        VMC4 BARR Z_STAGE(1, (t + 4) * 32) Z_COMPUTE(2) LGC0
    }
    VMC4 BARR Z_COMPUTE(0) LGC0          // tile 30
    VMC0 BARR Z_COMPUTE(1)               // tile 31
    __syncthreads();   // full drain once; smem reused as epilogue stage

    // bias (all paths)
    const float bs0 = bias[n0 + wx * 64 + l15];
    const float bs1 = bias[n0 + wx * 64 + 16 + l15];
    const float bs2 = bias[n0 + wx * 64 + 32 + l15];
    const float bs3 = bias[n0 + wx * 64 + 48 + l15];
#define Z_BIAS(mi) c##mi##0 += bs0; c##mi##1 += bs1; c##mi##2 += bs2; c##mi##3 += bs3;
    FOR_M(Z_BIAS)

    if (z < 2) {
        // ---- q/k: rmsnorm (per 64-dim head row) + rope + store ----
        const float nww0 = nwp[l15],      nww1 = nwp[16 + l15];
        const float nww2 = nwp[32 + l15], nww3 = nwp[48 + l15];
        const float lf0 = expf(-(float)l15 * 0.28782313662425572f);      // ln(1e4)/32
        const float lf1 = expf(-(float)(l15 + 16) * 0.28782313662425572f);

#define Z_S2(mi) f32x4 s2_##mi = c##mi##0*c##mi##0 + c##mi##1*c##mi##1 + \
                                 c##mi##2*c##mi##2 + c##mi##3*c##mi##3; \
        s2_##mi = s2_##mi + shfl_xor4(s2_##mi, 1); \
        s2_##mi = s2_##mi + shfl_xor4(s2_##mi, 2); \
        s2_##mi = s2_##mi + shfl_xor4(s2_##mi, 4); \
        s2_##mi = s2_##mi + shfl_xor4(s2_##mi, 8); \
        s2_##mi = rsq4(s2_##mi);
        FOR_M(Z_S2)

#define Z_ROPE_ONE(mi,ni,NW,CS,SN) { \
            float vn = c##mi##ni[r] * s2v[r] * NW; \
            float pt = __shfl_xor(vn, 1); \
            float rot = (lane & 1) ? pt : -pt; \
            smem[mrow * SS + wx * 64 + (ni) * 16 + l15] = f2bf((vn * (CS) + rot * (SN)) * 0.125f); }
#define Z_ROPE_MI(mi) { f32x4 s2v = s2_##mi; \
            _Pragma("unroll") \
            for (int r = 0; r < 4; r++) { \
                const int mrow = wy * 64 + (mi) * 16 + quad * 4 + r; \
                const float t = (float)((m0 + mrow) & 2047); \
                const float a0 = t * lf0, a1 = t * lf1; \
                const float cs0 = cosf(a0), sn0 = sinf(a0); \
                const float cs1 = cosf(a1), sn1 = sinf(a1); \
                Z_ROPE_ONE(mi,0,nww0,cs0,sn0) Z_ROPE_ONE(mi,1,nww1,cs1,sn1) \
                Z_ROPE_ONE(mi,2,nww2,cs0,sn0) Z_ROPE_ONE(mi,3,nww3,cs1,sn1) } }
        FOR_M(Z_ROPE_MI)

        __syncthreads();
        unsigned short* dst = z ? kb : qb;
#pragma unroll
        for (int it = 0; it < 8; it++) {
            const int linear = tid + it * 256;
            const int row = linear >> 4, cb = linear & 15;
            *(bf16x8*)(dst + (size_t)(m0 + row) * 1024 + n0 + cb * 8) =
                *(const bf16x8*)&smem[row * SS + cb * 8];
        }
    } else {
        // ---- v: transposed per-head store ----
#define Z_VST(mi,ni) { _Pragma("unroll") \
            for (int r = 0; r < 4; r++) { \
                const int mrow = wy * 64 + (mi) * 16 + quad * 4 + r; \
                smem[(wx * 64 + (ni) * 16 + l15) * SS + mrow] = f2bf(c##mi##ni[r]); } }
        FOR_MN(Z_VST)
        __syncthreads();
        const int b = m0 >> 11, tok0 = m0 & 2047;
#pragma unroll
        for (int it = 0; it < 8; it++) {
            const int linear = tid + it * 256;
            const int rowd = linear >> 4, cb = linear & 15;
            const int head_g = (n0 >> 6) + (rowd >> 6);
            const int d = rowd & 63;
            *(bf16x8*)(vT + (((size_t)b * 16 + head_g) * 64 + d) * 2048 + tok0 + cb * 8) =
                *(const bf16x8*)&smem[rowd * SS + cb * 8];
        }
    }
}

// ---------------------------------------------------------------------------
// Output GEMM + residual. r21: r17 geometry (128x128, 4 waves, wave 64x64,
// 3 blk/CU) + static 3-buf depth-2 vmcnt(4) pipeline (r19's proven unroll).
// ---------------------------------------------------------------------------
__global__ __launch_bounds__(256, 3) void gemm_out(
    const unsigned short* __restrict__ zb,
    const unsigned short* __restrict__ Wob,
    const float* __restrict__ x, float* __restrict__ out, int M)
{
    const int K = 1024;
    __shared__ unsigned short smem[24576];   // 3 bufs x (A[128][32] + W[128][32])
    const int tid = threadIdx.x;
    const int n0 = blockIdx.x * 128;
    const int m0 = blockIdx.y * 128;
    const int lane = tid & 63, wid = tid >> 6;
    const int wy = wid >> 1, wx = wid & 1;       // wave = 64m x 64n
    const int l15 = lane & 15, quad = lane >> 4;
    const int r16 = lane >> 2;
    const int c8  = (lane & 3) * 8;

#define G_DECL_ACC(mi,ni) f32x4 c##mi##ni = {0.f, 0.f, 0.f, 0.f};
    FOR_MN(G_DECL_ACC)

#define O_STAGE(BUF, KT) { \
        unsigned short* dstb = smem + (BUF) * 8192; \
        _Pragma("unroll") \
        for (int j = 0; j < 4; j++) { \
            const int ch = wid * 4 + j; \
            const int mat = ch >> 3; \
            const int row = (ch & 7) * 16 + r16; \
            const unsigned short* g = mat \
                ? Wob + (size_t)(n0 + row) * K + (KT) + c8 \
                : zb  + (size_t)(m0 + row) * K + (KT) + c8; \
            cp16(g, &dstb[ch * 512]); \
        } }

#define O_COMPUTE(BUF) { \
        const unsigned short* As_ = smem + (BUF) * 8192; \
        const unsigned short* Bs_ = As_ + 4096; \
        const bf16x8 a0 = *(const bf16x8*)&As_[(wy * 64 +  0 + l15) * 32 + quad * 8]; \
        const bf16x8 a1 = *(const bf16x8*)&As_[(wy * 64 + 16 + l15) * 32 + quad * 8]; \
        const bf16x8 a2 = *(const bf16x8*)&As_[(wy * 64 + 32 + l15) * 32 + quad * 8]; \
        const bf16x8 a3 = *(const bf16x8*)&As_[(wy * 64 + 48 + l15) * 32 + quad * 8]; \
        const bf16x8 b0 = *(const bf16x8*)&Bs_[(wx * 64 +  0 + l15) * 32 + quad * 8]; \
        const bf16x8 b1 = *(const bf16x8*)&Bs_[(wx * 64 + 16 + l15) * 32 + quad * 8]; \
        const bf16x8 b2 = *(const bf16x8*)&Bs_[(wx * 64 + 32 + l15) * 32 + quad * 8]; \
        const bf16x8 b3 = *(const bf16x8*)&Bs_[(wx * 64 + 48 + l15) * 32 + quad * 8]; \
        MF(c00,a0,b0) MF(c01,a0,b1) MF(c02,a0,b2) MF(c03,a0,b3) \
        MF(c10,a1,b0) MF(c11,a1,b1) MF(c12,a1,b2) MF(c13,a1,b3) \
        MF(c20,a2,b0) MF(c21,a2,b1) MF(c22,a2,b2) MF(c23,a2,b3) \
        MF(c30,a3,b0) MF(c31,a3,b1) MF(c32,a3,b2) MF(c33,a3,b3) }

    O_STAGE(0, 0)
    O_STAGE(1, 32)
    for (int p = 0; p < 10; ++p) {
        const int t = p * 3;
        VMC4 BARR O_STAGE(2, (t + 2) * 32) O_COMPUTE(0) LGC0
        VMC4 BARR O_STAGE(0, (t + 3) * 32) O_COMPUTE(1) LGC0
        VMC4 BARR O_STAGE(1, (t + 4) * 32) O_COMPUTE(2) LGC0
    }
    VMC4 BARR O_COMPUTE(0) LGC0          // tile 30
    VMC0 BARR O_COMPUTE(1)               // tile 31

#define G_OUTST(mi,ni) { _Pragma("unroll") \
        for (int r = 0; r < 4; r++) { \
            const int m = m0 + wy * 64 + (mi) * 16 + quad * 4 + r; \
            const int n = n0 + wx * 64 + (ni) * 16 + l15; \
            out[(size_t)m * 1024 + n] = c##mi##ni[r] + x[(size_t)m * 1024 + n]; } }
    FOR_MN(G_OUTST)
}

// ---------------------------------------------------------------------------
// Causal quadratic attention. r18: QBLK=64 (4 waves x 16 q-rows), grid
// 1024 = 32 qt x 32 bh, 4 blocks/CU, balanced half-remap (31-x, x).
// setprio around MFMA clusters. Mask only at kt==qt. (unchanged)
// ---------------------------------------------------------------------------
__global__ __launch_bounds__(256, 4) void attn_mfma(
    const unsigned short* __restrict__ qb, const unsigned short* __restrict__ kb,
    const unsigned short* __restrict__ vT, unsigned short* __restrict__ zb)
{
    __shared__ unsigned short Qs[64 * 72];
    __shared__ unsigned short Ks[64 * 72];
    __shared__ unsigned short Vs[64 * 72];   // rows = d, cols = k-token
    __shared__ unsigned short Pm[64 * 72];
    const int tid = threadIdx.x;

    // ---- balance remap: qt in 0..31 (64-row tiles); pair (31-x, x) ----
    const int bid = blockIdx.x;
    const int halfsz = gridDim.x >> 1;              // 512
    const int half = (bid >= halfsz) ? 1 : 0;
    const int r = bid - half * halfsz;              // 0..511
    const int qt = half ? (r & 15) : 31 - (r & 15);
    const int bh = r >> 4;                          // 0..31

    const int b = bh >> 4, h = bh & 15;
    const int lane = tid & 63, wq = tid >> 6;       // wq 0..3: 16 q-rows each
    const int l15 = lane & 15, quad = lane >> 4;
    const size_t tokbase = (size_t)b * 2048;
    const int q0 = qt * 64;

#pragma unroll
    for (int j = 0; j < 2; j++) {
        const int u = tid + j * 256;
        const int row = u >> 3, seg = (u & 7) * 8;
        bf16x8 v = *(const bf16x8*)(qb + (tokbase + q0 + row) * 1024 + h * 64 + seg);
        *(bf16x8*)&Qs[row * 72 + seg] = v;
    }
    __syncthreads();
    const bf16x8 aq0 = *(const bf16x8*)&Qs[(wq * 16 + l15) * 72 + quad * 8];
    const bf16x8 aq1 = *(const bf16x8*)&Qs[(wq * 16 + l15) * 72 + 32 + quad * 8];

    const int kr = tid >> 3;                        // 0..31
    const int sg = (tid & 7) * 8;

    bf16x8 pk0, pk1, pv0, pv1;
#define A_GLB(KT) { \
        pk0 = *(const bf16x8*)(kb + (tokbase + (KT) * 64 + kr) * 1024 + h * 64 + sg); \
        pk1 = *(const bf16x8*)(kb + (tokbase + (KT) * 64 + kr + 32) * 1024 + h * 64 + sg); \
        pv0 = *(const bf16x8*)(vT + ((size_t)bh * 64 + kr) * 2048 + (KT) * 64 + sg); \
        pv1 = *(const bf16x8*)(vT + ((size_t)bh * 64 + kr + 32) * 2048 + (KT) * 64 + sg); }

    f32x4 z_0 = {0.f,0.f,0.f,0.f}, z_1 = {0.f,0.f,0.f,0.f};
    f32x4 z_2 = {0.f,0.f,0.f,0.f}, z_3 = {0.f,0.f,0.f,0.f};

    const int nkt = qt + 1;
    A_GLB(0)
    for (int kt = 0; kt < nkt; kt++) {
        __syncthreads();
        *(bf16x8*)&Ks[kr * 72 + sg] = pk0;
        *(bf16x8*)&Ks[(kr + 32) * 72 + sg] = pk1;
        *(bf16x8*)&Vs[kr * 72 + sg] = pv0;
        *(bf16x8*)&Vs[(kr + 32) * 72 + sg] = pv1;
        __syncthreads();
        if (kt + 1 < nkt) A_GLB(kt + 1)

        f32x4 s_0 = {0.f,0.f,0.f,0.f}, s_1 = {0.f,0.f,0.f,0.f};
        f32x4 s_2 = {0.f,0.f,0.f,0.f}, s_3 = {0.f,0.f,0.f,0.f};
#define A_QKH(KS, AQ) { \
        bf16x8 b0 = *(const bf16x8*)&Ks[(l15) * 72 + (KS) * 32 + quad * 8]; \
        bf16x8 b1 = *(const bf16x8*)&Ks[(16 + l15) * 72 + (KS) * 32 + quad * 8]; \
        bf16x8 b2 = *(const bf16x8*)&Ks[(32 + l15) * 72 + (KS) * 32 + quad * 8]; \
        bf16x8 b3 = *(const bf16x8*)&Ks[(48 + l15) * 72 + (KS) * 32 + quad * 8]; \
        MF(s_0, AQ, b0) MF(s_1, AQ, b1) MF(s_2, AQ, b2) MF(s_3, AQ, b3) }
        __builtin_amdgcn_s_setprio(1);
        A_QKH(0, aq0)
        A_QKH(1, aq1)
        __builtin_amdgcn_s_setprio(0);

        const bool needmask = (kt == qt);
#define A_PSTORE(n) { \
        f32x4 p4 = s_##n * s_##n; \
        if (needmask) { _Pragma("unroll") \
            for (int r2 = 0; r2 < 4; r2++) \
                if (kt * 64 + (n) * 16 + l15 > q0 + wq * 16 + quad * 4 + r2) p4[r2] = 0.f; } \
        _Pragma("unroll") \
        for (int r2 = 0; r2 < 4; r2++) \
            Pm[(wq * 16 + quad * 4 + r2) * 72 + (n) * 16 + l15] = f2bf(p4[r2]); }
        A_PSTORE(0) A_PSTORE(1) A_PSTORE(2) A_PSTORE(3)

#define A_PVH(KS) { \
        bf16x8 ap = *(const bf16x8*)&Pm[(wq * 16 + l15) * 72 + (KS) * 32 + quad * 8]; \
        bf16x8 u0 = *(const bf16x8*)&Vs[(l15) * 72 + (KS) * 32 + quad * 8]; \
        bf16x8 u1 = *(const bf16x8*)&Vs[(16 + l15) * 72 + (KS) * 32 + quad * 8]; \
        bf16x8 u2 = *(const bf16x8*)&Vs[(32 + l15) * 72 + (KS) * 32 + quad * 8]; \
        bf16x8 u3 = *(const bf16x8*)&Vs[(48 + l15) * 72 + (KS) * 32 + quad * 8]; \
        MF(z_0, ap, u0) MF(z_1, ap, u1) MF(z_2, ap, u2) MF(z_3, ap, u3) }
        __builtin_amdgcn_s_setprio(1);
        A_PVH(0)
        A_PVH(1)
        __builtin_amdgcn_s_setprio(0);
    }

#define A_ZST(n) { _Pragma("unroll") \
        for (int r2 = 0; r2 < 4; r2++) \
            Pm[(wq * 16 + quad * 4 + r2) * 72 + (n) * 16 + l15] = f2bf(z_##n[r2]); }
    A_ZST(0) A_ZST(1) A_ZST(2) A_ZST(3)
#pragma unroll
    for (int it = 0; it < 2; it++) {
        const int linear = it * 64 + lane;
        const int row = linear >> 3, cb = linear & 7;
        *(bf16x8*)(zb + (tokbase + q0 + wq * 16 + row) * 1024 + h * 64 + cb * 8) =
            *(const bf16x8*)&Pm[(wq * 16 + row) * 72 + cb * 8];
    }
}

// ---------------------------------------------------------------------------
extern "C" void kernel_launch(void* const* d_in, const int* in_sizes, int n_in,
                              void* d_out, int out_size, void* d_ws, size_t ws_size,
                              hipStream_t stream)
{
    const float* x  = (const float*)d_in[0];
    const float* Wq = (const float*)d_in[1];
    const float* bq = (const float*)d_in[2];
    const float* Wk = (const float*)d_in[3];
    const float* bk = (const float*)d_in[4];
    const float* Wv = (const float*)d_in[5];
    const float* bv = (const float*)d_in[6];
    const float* Wo = (const float*)d_in[7];
    const float* nw = (const float*)d_in[8];
    float* out = (float*)d_out;

    const int D = 1024;
    const int M = in_sizes[0] / D;   // B*S = 4096

    unsigned short* xbb = (unsigned short*)d_ws;         // M*D
    unsigned short* Wqb = xbb + (size_t)M * D;           // D*D
    unsigned short* Wkb = Wqb + (size_t)D * D;
    unsigned short* Wvb = Wkb + (size_t)D * D;
    unsigned short* Wob = Wvb + (size_t)D * D;
    unsigned short* qbw = Wob + (size_t)D * D;           // M*D
    unsigned short* kbw = qbw + (size_t)M * D;
    unsigned short* vTw = kbw + (size_t)M * D;
    unsigned short* zbw = vTw + (size_t)M * D;

    const int nx4 = M * D / 4, nw4 = D * D / 4;
    const int ncvt = nx4 + 4 * nw4;
    cvt_all<<<(ncvt + 255) / 256, 256, 0, stream>>>(
        x, Wq, Wk, Wv, Wo, xbb, Wqb, Wkb, Wvb, Wob, nx4, nw4);

    gemm_qkvz<<<dim3(768), 256, 0, stream>>>(
        xbb, Wqb, Wkb, Wvb, bq, bk, bv, nw, qbw, kbw, vTw);

    attn_mfma<<<dim3((M / 2048) * 16 * 32), 256, 0, stream>>>(qbw, kbw, vTw, zbw);

    gemm_out<<<dim3(D / 128, M / 128), 256, 0, stream>>>(zbw, Wob, x, out, M);
}